// Round 10
// baseline (455.504 us; speedup 1.0000x reference)
//
#include <hip/hip_runtime.h>

#define IMG   512
#define WT    64           // w-tile (lanes)
#define HT    64           // h per strip
#define NSTRIP (IMG / HT)  // 8 strips -> one WG integrates the FULL line
#define NT    512          // 8 waves
#define HC    8            // h-chunks per strip (one per wave)
#define HPER  (HT / HC)    // 8 samples per thread per strip
#define ROWS  96           // staged rows (worst-case strip span ~95)
#define PITCH_A 95         // c*s >= 0  (95 % 32 == 31: bank ~ jx - jy, lane-step |c|+s)
#define PITCH_B 97         // c*s <  0  (97 % 32 ==  1: bank ~ jx + jy, lane-step |c|+s)
#define BUF_FLOATS (ROWS * PITCH_B + 8)    // 9320 floats = 37.3 KB per buffer
// 2 buffers = 74.6 KB -> 2 WG/CU (16 waves). Pipeline replaces occupancy.

// Direct global->LDS DMA: wave-uniform LDS base, HW adds lane*4.
__device__ __forceinline__ void gload_lds4(const float* g, float* l) {
    __builtin_amdgcn_global_load_lds((const __attribute__((address_space(1))) void*)g,
                                     (__attribute__((address_space(3))) void*)l,
                                     4, 0, 0);
}

// single-instruction fractional part (x >= 0 here)
__device__ __forceinline__ float vfract(float x) {
    float r;
    asm("v_fract_f32 %0, %1" : "=v"(r) : "v"(x));
    return r;
}

template<int PITCH>
__device__ __forceinline__ float lerp4(const float* __restrict__ tile,
                                       float fx, float fy) {
    int jx = (int)fx;                  // fx,fy >= 1: trunc == floor
    int jy = (int)fy;
    const float* __restrict__ p = tile + (__mul24(jy, PITCH) + jx);
    float v00 = p[0];
    float v01 = p[1];                  // ds_read2_b32 (0,1)
    float v10 = p[PITCH];
    float v11 = p[PITCH + 1];          // ds_read2_b32 (PITCH,PITCH+1)
    float wx1 = vfract(fx);
    float wy1 = vfract(fy);
    float lx0 = fmaf(wx1, v01 - v00, v00);
    float lx1 = fmaf(wx1, v11 - v10, v10);
    return fmaf(wy1, lx1 - lx0, lx0);
}

// Issue the DMA (and any border zero-fill) for one strip. NO barrier inside:
// caller's loop barrier both drains vmcnt and orders buffer reuse.
// Border path: each row is zero-written and DMA'd by the SAME wave, with an
// lgkmcnt(0) between -> no cross-wave ordering needed.
template<int PITCH>
__device__ __forceinline__ void stage_strip(
    const float* __restrict__ img, float* __restrict__ buf,
    int xmin, int ymin, int nxn, int nyn, int lane, int wv)
{
    bool border = (xmin < 0) | (ymin < 0) | (xmin + nxn > IMG) | (ymin + nyn > IMG);
    if (!border) {
        for (int yy = wv; yy < nyn; yy += HC) {
            const float* __restrict__ src = img + (size_t)(ymin + yy) * IMG + xmin;
            float* dst = buf + __mul24(yy, PITCH);
            gload_lds4(src + lane, dst);                       // nxn >= 66
            if (64 + lane < nxn) gload_lds4(src + 64 + lane, dst + 64);
        }
    } else {
        int gx0 = max(xmin, 0), gx1 = min(xmin + nxn, IMG);
        int lx0 = gx0 - xmin, lxn = gx1 - gx0;
        // zero-fill this wave's rows (covers out-of-image rows and margins)
        for (int yy = wv; yy < nyn; yy += HC) {
            float* dst = buf + __mul24(yy, PITCH);
            for (int xx = lane; xx < nxn; xx += 64) dst[xx] = 0.0f;
        }
        asm volatile("s_waitcnt lgkmcnt(0)" ::: "memory");     // zeros land before DMA
        if (lxn > 0) {
            for (int yy = wv; yy < nyn; yy += HC) {
                int gy = ymin + yy;
                if ((unsigned)gy < (unsigned)IMG) {
                    const float* __restrict__ src = img + (size_t)gy * IMG + gx0;
                    float* dst = buf + (__mul24(yy, PITCH) + lx0);
                    for (int k = 0; k < lxn; k += 64)
                        if (k + lane < lxn) gload_lds4(src + k + lane, dst + k);
                }
            }
        }
    }
}

// Full line integral, software-pipelined over h-strips:
//   issue DMA(st+1 -> bufB) ; compute(st from bufA) ; barrier (drain+reuse)
template<int PITCH>
__device__ __forceinline__ void radon_body(
    const float* __restrict__ img, float* __restrict__ lds,
    float* __restrict__ out, float s, float c,
    int n, int a, int w0, int A)
{
    float* buf[2] = { lds, lds + BUF_FLOATS };
    int lane = threadIdx.x & 63;
    int wv   = threadIdx.x >> 6;

    // ix(w,h) = c*u + s*t + 255.5, iy = -s*u + c*t + 255.5; u,t = coord-255.5
    float u   = (float)(w0 + lane) - 255.5f;
    float uc  = (float)w0 + (31.5f - 255.5f);
    float ex  = (fabsf(c) + s) * 31.5f;          // half-extent (square strip)
    float ixc = fmaf(c, uc, fmaf(s, (31.5f - 255.5f), 255.5f));
    float iyc = fmaf(-s, uc, fmaf(c, (31.5f - 255.5f), 255.5f));

    // bbox of strip 0 + prologue stage
    int xminA = (int)floorf(ixc - ex) - 1;
    int yminA = (int)floorf(iyc - ex) - 1;
    int nxnA  = min((int)floorf(ixc + ex) - xminA + 3, PITCH);
    int nynA  = min((int)floorf(iyc + ex) - yminA + 3, ROWS);
    stage_strip<PITCH>(img, buf[0], xminA, yminA, nxnA, nynA, lane, wv);
    __syncthreads();                             // buf0 ready (vmcnt drained)

    float acc = 0.0f;
    for (int st = 0; st < NSTRIP; ++st) {
        // ---- issue next strip's DMA into the other buffer (no wait) ----
        int xminB = 0, yminB = 0, nxnB = 0, nynB = 0;
        if (st + 1 < NSTRIP) {
            float ixn = ixc + s * (float)HT;     // next strip center
            float iyn = iyc + c * (float)HT;
            xminB = (int)floorf(ixn - ex) - 1;
            yminB = (int)floorf(iyn - ex) - 1;
            nxnB  = min((int)floorf(ixn + ex) - xminB + 3, PITCH);
            nynB  = min((int)floorf(iyn + ex) - yminB + 3, ROWS);
            stage_strip<PITCH>(img, buf[(st + 1) & 1], xminB, yminB, nxnB, nynB, lane, wv);
            ixc = ixn; iyc = iyn;
        }

        // ---- compute strip st from buf[st&1] ----
        const float* __restrict__ t = buf[st & 1];
        float tb = (float)(st * HT + wv * HPER) - 255.5f;
        float fx = fmaf(s, tb, fmaf(c,  u, 255.5f - (float)xminA));
        float fy = fmaf(c, tb, fmaf(-s, u, 255.5f - (float)yminA));
        #pragma unroll
        for (int b = 0; b < HPER / 4; ++b) {
            float fx0 = fx,       fy0 = fy;
            float fx1 = fx0 + s,  fy1 = fy0 + c;
            float fx2 = fx1 + s,  fy2 = fy1 + c;
            float fx3 = fx2 + s,  fy3 = fy2 + c;
            fx = fx3 + s;  fy = fy3 + c;
            acc += lerp4<PITCH>(t, fx0, fy0);
            acc += lerp4<PITCH>(t, fx1, fy1);
            acc += lerp4<PITCH>(t, fx2, fy2);
            acc += lerp4<PITCH>(t, fx3, fy3);
        }

        // one barrier per strip: (a) all reads of buf[st&1] done -> reusable;
        // (b) compiler-inserted vmcnt(0) drains next strip's DMA -> ready.
        __syncthreads();
        xminA = xminB; yminA = yminB;
    }

    // reduce 8 wave-partials per w; each output written exactly once
    lds[threadIdx.x] = acc;
    __syncthreads();
    if (threadIdx.x < WT) {
        float r = 0.0f;
        #pragma unroll
        for (int k = 0; k < HC; ++k) r += lds[k * WT + threadIdx.x];
        out[((size_t)n * IMG + w0 + threadIdx.x) * A + a] = r;
    }
}

__global__ __launch_bounds__(NT, 4) void radon_lds(
    const float* __restrict__ x, const float* __restrict__ theta,
    float* __restrict__ out, int N, int A)
{
    __shared__ float lds[2 * BUF_FLOATS];
    int a  = blockIdx.z % A;
    int n  = blockIdx.z / A;
    int w0 = blockIdx.x * WT;

    float rad = theta[a] * (3.14159265358979323846f / 180.0f);
    float s, c;
    __sincosf(rad, &s, &c);            // theta in [0,179] deg -> s >= 0

    const float* __restrict__ img = x + (size_t)n * (IMG * IMG);
    if (c * s >= 0.0f)
        radon_body<PITCH_A>(img, lds, out, s, c, n, a, w0, A);
    else
        radon_body<PITCH_B>(img, lds, out, s, c, n, a, w0, A);
}

extern "C" void kernel_launch(void* const* d_in, const int* in_sizes, int n_in,
                              void* d_out, int out_size, void* d_ws, size_t ws_size,
                              hipStream_t stream) {
    const float* x     = (const float*)d_in[0];
    const float* theta = (const float*)d_in[1];
    float* out = (float*)d_out;

    int A = in_sizes[1];                   // 180
    int N = in_sizes[0] / (IMG * IMG);     // 2

    dim3 grid(IMG / WT, 1, N * A);         // 8 x 1 x 360 = 2880 WGs
    radon_lds<<<grid, NT, 0, stream>>>(x, theta, out, N, A);
}

// Round 11
// 174.659 us; speedup vs baseline: 2.6080x; 2.6080x over previous
//
#include <hip/hip_runtime.h>

#define IMG   512
#define WT    64           // w-tile (lanes)
#define HT    64           // h per strip
#define NSTRIP (IMG / HT)  // 8 strips -> one WG integrates the FULL line
#define NT    512          // 8 waves
#define HC    8            // h-chunks per strip (one per wave)
#define HPER  (HT / HC)    // 8 samples per thread per strip
#define ROWS  96           // staged rows (worst-case strip span ~95)
#define PITCH_A 95         // c*s >= 0  (95 % 32 == 31: bank ~ jx - jy, lane-step |c|+s)
#define PITCH_B 97         // c*s <  0  (97 % 32 ==  1: bank ~ jx + jy, lane-step |c|+s)
#define BUF_FLOATS (ROWS * PITCH_B + 8)    // 9320 floats = 37.3 KB per buffer

// Direct global->LDS DMA: wave-uniform LDS base, HW adds lane*4.
__device__ __forceinline__ void gload_lds4(const float* g, float* l) {
    __builtin_amdgcn_global_load_lds((const __attribute__((address_space(1))) void*)g,
                                     (__attribute__((address_space(3))) void*)l,
                                     4, 0, 0);
}

// single-instruction fractional part (x >= 0 here)
__device__ __forceinline__ float vfract(float x) {
    float r;
    asm("v_fract_f32 %0, %1" : "=v"(r) : "v"(x));
    return r;
}

template<int PITCH>
__device__ __forceinline__ float lerp4(const float* __restrict__ tile,
                                       float fx, float fy) {
    int jx = (int)fx;                  // fx,fy >= 1: trunc == floor
    int jy = (int)fy;
    const float* __restrict__ p = tile + (__mul24(jy, PITCH) + jx);
    float v00 = p[0];
    float v01 = p[1];                  // ds_read2_b32 (0,1)
    float v10 = p[PITCH];
    float v11 = p[PITCH + 1];          // ds_read2_b32 (PITCH,PITCH+1)
    float wx1 = vfract(fx);
    float wy1 = vfract(fy);
    float lx0 = fmaf(wx1, v01 - v00, v00);
    float lx1 = fmaf(wx1, v11 - v10, v10);
    return fmaf(wy1, lx1 - lx0, lx0);
}

// Strip bbox in image coords from strip index (WG-uniform arithmetic).
template<int PITCH>
__device__ __forceinline__ void strip_bbox(float ixc0, float iyc0, float ex,
                                           float s, float c, int st,
                                           int& xmin, int& ymin, int& nxn, int& nyn) {
    float ixc = fmaf(s, (float)(HT * st), ixc0);
    float iyc = fmaf(c, (float)(HT * st), iyc0);
    xmin = (int)floorf(ixc - ex) - 1;
    ymin = (int)floorf(iyc - ex) - 1;
    nxn  = min((int)floorf(ixc + ex) - xmin + 3, PITCH);
    nyn  = min((int)floorf(iyc + ex) - ymin + 3, ROWS);
}

// Issue the DMA (and any border zero-fill) for one strip. NO barrier inside:
// the caller's loop barrier drains vmcnt and orders buffer reuse.
// Border rows are zero-written and DMA'd by the SAME wave (lgkmcnt between).
template<int PITCH>
__device__ __forceinline__ void stage_strip(
    const float* __restrict__ img, float* __restrict__ buf,
    int xmin, int ymin, int nxn, int nyn, int lane, int wv)
{
    bool border = (xmin < 0) | (ymin < 0) | (xmin + nxn > IMG) | (ymin + nyn > IMG);
    if (!border) {
        for (int yy = wv; yy < nyn; yy += HC) {
            const float* __restrict__ src = img + (size_t)(ymin + yy) * IMG + xmin;
            float* dst = buf + __mul24(yy, PITCH);
            gload_lds4(src + lane, dst);                       // nxn >= 66
            if (64 + lane < nxn) gload_lds4(src + 64 + lane, dst + 64);
        }
    } else {
        int gx0 = max(xmin, 0), gx1 = min(xmin + nxn, IMG);
        int lx0 = gx0 - xmin, lxn = gx1 - gx0;
        for (int yy = wv; yy < nyn; yy += HC) {
            float* dst = buf + __mul24(yy, PITCH);
            for (int xx = lane; xx < nxn; xx += 64) dst[xx] = 0.0f;
        }
        asm volatile("s_waitcnt lgkmcnt(0)" ::: "memory");     // zeros land before DMA
        if (lxn > 0) {
            for (int yy = wv; yy < nyn; yy += HC) {
                int gy = ymin + yy;
                if ((unsigned)gy < (unsigned)IMG) {
                    const float* __restrict__ src = img + (size_t)gy * IMG + gx0;
                    float* dst = buf + (__mul24(yy, PITCH) + lx0);
                    for (int k = 0; k < lxn; k += 64)
                        if (k + lane < lxn) gload_lds4(src + k + lane, dst + k);
                }
            }
        }
    }
}

template<int PITCH>
__device__ __forceinline__ float compute_strip(
    const float* __restrict__ buf, int st, int xmin, int ymin,
    float u, float s, float c, int wv)
{
    float tb = (float)(st * HT + wv * HPER) - 255.5f;
    float fx = fmaf(s, tb, fmaf(c,  u, 255.5f - (float)xmin));
    float fy = fmaf(c, tb, fmaf(-s, u, 255.5f - (float)ymin));
    float acc = 0.0f;
    #pragma unroll
    for (int b = 0; b < HPER / 4; ++b) {
        float fx0 = fx,       fy0 = fy;
        float fx1 = fx0 + s,  fy1 = fy0 + c;
        float fx2 = fx1 + s,  fy2 = fy1 + c;
        float fx3 = fx2 + s,  fy3 = fy2 + c;
        fx = fx3 + s;  fy = fy3 + c;
        acc += lerp4<PITCH>(buf, fx0, fy0);
        acc += lerp4<PITCH>(buf, fx1, fy1);
        acc += lerp4<PITCH>(buf, fx2, fy2);
        acc += lerp4<PITCH>(buf, fx3, fy3);
    }
    return acc;
}

// Software-pipelined full-line integral. Double buffer = two STATICALLY
// DISTINCT __shared__ arrays (runtime-selected LDS pointers defeat
// address-space inference -> FLAT loads; observed round 10).
template<int PITCH>
__device__ __forceinline__ void radon_body(
    const float* __restrict__ img,
    float* __restrict__ bufA, float* __restrict__ bufB, float* __restrict__ red,
    float* __restrict__ out, float s, float c, int n, int a, int w0, int A)
{
    int lane = threadIdx.x & 63;
    int wv   = threadIdx.x >> 6;

    // ix(w,h) = c*u + s*t + 255.5, iy = -s*u + c*t + 255.5; u,t = coord-255.5
    float u    = (float)(w0 + lane) - 255.5f;
    float uc   = (float)w0 + (31.5f - 255.5f);
    float ex   = (fabsf(c) + s) * 31.5f;               // half-extent (square strip)
    float ixc0 = fmaf(c, uc, fmaf(s, (31.5f - 255.5f), 255.5f));
    float iyc0 = fmaf(-s, uc, fmaf(c, (31.5f - 255.5f), 255.5f));

    int xa, ya, na_x, na_y, xb, yb, nb_x, nb_y;
    strip_bbox<PITCH>(ixc0, iyc0, ex, s, c, 0, xa, ya, na_x, na_y);
    stage_strip<PITCH>(img, bufA, xa, ya, na_x, na_y, lane, wv);
    __syncthreads();                                   // buf A ready

    float acc = 0.0f;
    for (int st = 0; st < NSTRIP; st += 2) {
        // issue DMA for st+1 into B, then compute st from A
        strip_bbox<PITCH>(ixc0, iyc0, ex, s, c, st + 1, xb, yb, nb_x, nb_y);
        stage_strip<PITCH>(img, bufB, xb, yb, nb_x, nb_y, lane, wv);
        acc += compute_strip<PITCH>(bufA, st, xa, ya, u, s, c, wv);
        __syncthreads();   // drains B's DMA (after compute); A now reusable

        // issue DMA for st+2 into A, then compute st+1 from B
        if (st + 2 < NSTRIP) {
            strip_bbox<PITCH>(ixc0, iyc0, ex, s, c, st + 2, xa, ya, na_x, na_y);
            stage_strip<PITCH>(img, bufA, xa, ya, na_x, na_y, lane, wv);
        }
        acc += compute_strip<PITCH>(bufB, st + 1, xb, yb, u, s, c, wv);
        __syncthreads();   // drains A's DMA; B reusable
    }

    // reduce 8 wave-partials per w; each output written exactly once
    red[threadIdx.x] = acc;
    __syncthreads();
    if (threadIdx.x < WT) {
        float r = 0.0f;
        #pragma unroll
        for (int k = 0; k < HC; ++k) r += red[k * WT + threadIdx.x];
        out[((size_t)n * IMG + w0 + threadIdx.x) * A + a] = r;
    }
}

__global__ __launch_bounds__(NT, 4) void radon_lds(
    const float* __restrict__ x, const float* __restrict__ theta,
    float* __restrict__ out, int N, int A)
{
    __shared__ float bufA[BUF_FLOATS];
    __shared__ float bufB[BUF_FLOATS];
    __shared__ float red[NT];
    int a  = blockIdx.z % A;
    int n  = blockIdx.z / A;
    int w0 = blockIdx.x * WT;

    float rad = theta[a] * (3.14159265358979323846f / 180.0f);
    float s, c;
    __sincosf(rad, &s, &c);            // theta in [0,179] deg -> s >= 0

    const float* __restrict__ img = x + (size_t)n * (IMG * IMG);
    if (c * s >= 0.0f)
        radon_body<PITCH_A>(img, bufA, bufB, red, out, s, c, n, a, w0, A);
    else
        radon_body<PITCH_B>(img, bufA, bufB, red, out, s, c, n, a, w0, A);
}

extern "C" void kernel_launch(void* const* d_in, const int* in_sizes, int n_in,
                              void* d_out, int out_size, void* d_ws, size_t ws_size,
                              hipStream_t stream) {
    const float* x     = (const float*)d_in[0];
    const float* theta = (const float*)d_in[1];
    float* out = (float*)d_out;

    int A = in_sizes[1];                   // 180
    int N = in_sizes[0] / (IMG * IMG);     // 2

    dim3 grid(IMG / WT, 1, N * A);         // 8 x 1 x 360 = 2880 WGs
    radon_lds<<<grid, NT, 0, stream>>>(x, theta, out, N, A);
}

// Round 13
// 127.010 us; speedup vs baseline: 3.5864x; 1.3752x over previous
//
#include <hip/hip_runtime.h>

#define IMG    512
#define WT     64          // w-tile (lanes)
#define HT     64          // h per strip
#define NSTRIP (IMG / HT)  // 8 strips -> one WG integrates the FULL line
#define NT     512         // 8 waves
#define HC     8           // h-chunks per strip (one per wave)
#define HPER   (HT / HC)   // 8 samples per thread per strip
#define ROWS   96          // staged rows (worst-case strip span ~95)
#define PITCH  97          // 97 % 32 == 1. For theta <= 90 rows are stored
                           // FLIPPED, negating the residue -> bank step is
                           // |c|+s >= 1 per lane for every angle.
#define BUF_FLOATS (ROWS * PITCH + 8)   // 9320 floats = 37.3 KB -> 4 WG/CU

// Direct global->LDS DMA: wave-uniform LDS base, HW adds lane*4.
__device__ __forceinline__ void gload_lds4(const float* g, float* l) {
    __builtin_amdgcn_global_load_lds((const __attribute__((address_space(1))) void*)g,
                                     (__attribute__((address_space(3))) void*)l, 4, 0, 0);
}

// single-instruction fractional part
__device__ __forceinline__ float vfract(float x) {
    float r;
    asm("v_fract_f32 %0, %1" : "=v"(r) : "v"(x));
    return r;
}

// Standard bilinear from the tile. Works unchanged for flipped storage:
// with fyF = (nyn-1) - fy the taps swap roles and weights swap complement,
// reproducing the original sum exactly (algebraic identity).
__device__ __forceinline__ float lerp4(const float* __restrict__ tile,
                                       float fx, float fy) {
    int jx = (int)fx;                  // fx,fy >= 1: trunc == floor
    int jy = (int)fy;
    const float* __restrict__ p = tile + (__mul24(jy, PITCH) + jx);
    float v00 = p[0];
    float v01 = p[1];                  // ds_read2_b32 (0,1)
    float v10 = p[PITCH];
    float v11 = p[PITCH + 1];          // ds_read2_b32 (PITCH,PITCH+1)
    float wx1 = vfract(fx);
    float wy1 = vfract(fy);
    float lx0 = fmaf(wx1, v01 - v00, v00);
    float lx1 = fmaf(wx1, v11 - v10, v10);
    return fmaf(wy1, lx1 - lx0, lx0);
}

__global__ __launch_bounds__(NT, 8) void radon_lds(
    const float* __restrict__ x, const float* __restrict__ theta,
    float* __restrict__ out, int N, int A)
{
    __shared__ float tile[BUF_FLOATS];
    __shared__ float red[NT];
    int a  = blockIdx.z % A;
    int n  = blockIdx.z / A;
    int w0 = blockIdx.x * WT;

    float rad = theta[a] * 0.017453292519943295f;
    float s, c;
    __sincosf(rad, &s, &c);            // theta in [0,179] deg -> s >= 0

    bool  flip = (c >= 0.0f);          // theta <= 90: flip rows (bank parity)
    float cE   = flip ? -c : c;        // compute-side y march step

    const float* __restrict__ img = x + (size_t)n * (IMG * IMG);
    int lane = threadIdx.x & 63;
    int wv   = threadIdx.x >> 6;

    // ix(w,h) = c*u + s*t + 255.5, iy = -s*u + c*t + 255.5; u,t = coord-255.5
    float u   = (float)(w0 + lane) - 255.5f;
    float uc  = (float)w0 + (31.5f - 255.5f);
    float ex  = (fabsf(c) + s) * 31.5f;          // half-extent (square strip)
    float ixc = fmaf(c, uc, fmaf(s, (31.5f - 255.5f), 255.5f));
    float iyc = fmaf(-s, uc, fmaf(c, (31.5f - 255.5f), 255.5f));

    float acc = 0.0f;
    for (int st = 0; st < NSTRIP; ++st) {
        int xmin = (int)floorf(ixc - ex) - 1;
        int ymin = (int)floorf(iyc - ex) - 1;
        int nxn  = min((int)floorf(ixc + ex) - xmin + 3, PITCH);  // 66..95
        int nyn  = min((int)floorf(iyc + ex) - ymin + 3, ROWS);

        if (st > 0) __syncthreads();             // prev strip's reads done

        bool border = (xmin < 0) | (ymin < 0) | (xmin + nxn > IMG) | (ymin + nyn > IMG);
        if (!border) {
            // interior: pure DMA; row yy stored at slot (flip ? nyn-1-yy : yy)
            for (int yy = wv; yy < nyn; yy += HC) {
                const float* __restrict__ src = img + (size_t)(ymin + yy) * IMG + xmin;
                float* dst = tile + __mul24(flip ? (nyn - 1 - yy) : yy, PITCH);
                gload_lds4(src + lane, dst);                       // nxn >= 66
                if (64 + lane < nxn) gload_lds4(src + 64 + lane, dst + 64);
            }
        } else {
            // border: zero + DMA by the SAME wave (lgkmcnt orders within wave)
            int gx0 = max(xmin, 0), gx1 = min(xmin + nxn, IMG);
            int lx0 = gx0 - xmin, lxn = gx1 - gx0;
            for (int yy = wv; yy < nyn; yy += HC) {
                float* dst = tile + __mul24(flip ? (nyn - 1 - yy) : yy, PITCH);
                for (int xx = lane; xx < nxn; xx += 64) dst[xx] = 0.0f;
            }
            asm volatile("s_waitcnt lgkmcnt(0)" ::: "memory");     // zeros landed
            if (lxn > 0) {
                for (int yy = wv; yy < nyn; yy += HC) {
                    int gy = ymin + yy;
                    if ((unsigned)gy < (unsigned)IMG) {
                        const float* __restrict__ src = img + (size_t)gy * IMG + gx0;
                        float* dst = tile + (__mul24(flip ? (nyn - 1 - yy) : yy, PITCH) + lx0);
                        for (int k = 0; k < lxn; k += 64)
                            if (k + lane < lxn) gload_lds4(src + k + lane, dst + k);
                    }
                }
            }
        }
        __syncthreads();                         // DMA drained (vmcnt0 + barrier)

        // 8 samples along h, 4-wide ILP batches
        float tb  = (float)(st * HT + wv * HPER) - 255.5f;
        float fx  = fmaf(s, tb, fmaf(c,  u, 255.5f - (float)xmin));
        float fyo = fmaf(c, tb, fmaf(-s, u, 255.5f - (float)ymin));
        float fy  = flip ? ((float)(nyn - 1) - fyo) : fyo;
        #pragma unroll
        for (int b = 0; b < HPER / 4; ++b) {
            float fx0 = fx,        fy0 = fy;
            float fx1 = fx0 + s,   fy1 = fy0 + cE;
            float fx2 = fx1 + s,   fy2 = fy1 + cE;
            float fx3 = fx2 + s,   fy3 = fy2 + cE;
            fx = fx3 + s;  fy = fy3 + cE;
            acc += lerp4(tile, fx0, fy0);
            acc += lerp4(tile, fx1, fy1);
            acc += lerp4(tile, fx2, fy2);
            acc += lerp4(tile, fx3, fy3);
        }

        ixc += s * (float)HT;                    // strip center advances along t
        iyc += c * (float)HT;
    }

    // reduce 8 wave-partials per w; each output written exactly once
    __syncthreads();
    red[threadIdx.x] = acc;
    __syncthreads();
    if (threadIdx.x < WT) {
        float r = 0.0f;
        #pragma unroll
        for (int k = 0; k < HC; ++k) r += red[k * WT + threadIdx.x];
        out[((size_t)n * IMG + w0 + threadIdx.x) * A + a] = r;
    }
}

extern "C" void kernel_launch(void* const* d_in, const int* in_sizes, int n_in,
                              void* d_out, int out_size, void* d_ws, size_t ws_size,
                              hipStream_t stream) {
    const float* x     = (const float*)d_in[0];
    const float* theta = (const float*)d_in[1];
    float* out = (float*)d_out;

    int A = in_sizes[1];                   // 180
    int N = in_sizes[0] / (IMG * IMG);     // 2

    dim3 grid(IMG / WT, 1, N * A);         // 8 x 1 x 360 = 2880 WGs
    radon_lds<<<grid, NT, 0, stream>>>(x, theta, out, N, A);
}

// Round 14
// 112.909 us; speedup vs baseline: 4.0343x; 1.1249x over previous
//
#include <hip/hip_runtime.h>

#define IMG    512
#define WT     64          // w-tile (lanes)
#define HT     64          // h per strip
#define NSTRIP (IMG / HT)  // 8 strips -> one WG integrates the FULL line
#define NT     512         // 8 waves
#define HC     8           // h-chunks per strip (one per wave)
#define HPER   (HT / HC)   // 8 samples per thread per strip
#define ROWS   96          // staged rows (worst-case strip span ~95)
#define PITCH_A 95         // c*s >= 0  (95 % 32 == 31: bank ~ jx - jy, lane-step |c|+s)
#define PITCH_B 97         // c*s <  0  (97 % 32 ==  1: bank ~ jx + jy, lane-step |c|+s)
#define BUF_FLOATS (ROWS * PITCH_B + 8)   // 9320 floats = 37.3 KB per image tile

// Direct global->LDS DMA: wave-uniform LDS base, HW adds lane*4.
__device__ __forceinline__ void gload_lds4(const float* g, float* l) {
    __builtin_amdgcn_global_load_lds((const __attribute__((address_space(1))) void*)g,
                                     (__attribute__((address_space(3))) void*)l, 4, 0, 0);
}

// single-instruction fractional part
__device__ __forceinline__ float vfract(float x) {
    float r;
    asm("v_fract_f32 %0, %1" : "=v"(r) : "v"(x));
    return r;
}

// Bilinear taps for BOTH images at one sample point: address/weights computed
// once, tap reads + lerp duplicated. tileB sits at a constant LDS offset from
// tileA, so addrB is one v_add.
template<int PITCH>
__device__ __forceinline__ void lerp_pair(const float* __restrict__ tA,
                                          const float* __restrict__ tB,
                                          float fx, float fy,
                                          float& a0, float& a1) {
    int jx = (int)fx;                  // fx,fy >= 1: trunc == floor
    int jy = (int)fy;
    int off = __mul24(jy, PITCH) + jx;
    const float* __restrict__ pA = tA + off;
    const float* __restrict__ pB = tB + off;
    float wx1 = vfract(fx);
    float wy1 = vfract(fy);
    float A00 = pA[0], A01 = pA[1];            // ds_read2 (0,1)
    float A10 = pA[PITCH], A11 = pA[PITCH+1];  // ds_read2 (P,P+1)
    float B00 = pB[0], B01 = pB[1];
    float B10 = pB[PITCH], B11 = pB[PITCH+1];
    float lA0 = fmaf(wx1, A01 - A00, A00);
    float lA1 = fmaf(wx1, A11 - A10, A10);
    float lB0 = fmaf(wx1, B01 - B00, B00);
    float lB1 = fmaf(wx1, B11 - B10, B10);
    a0 += fmaf(wy1, lA1 - lA0, lA0);
    a1 += fmaf(wy1, lB1 - lB0, lB0);
}

// One WG: full line integral for (w-tile, angle) for BOTH images.
// Staging geometry/addressing shared; two DMAs per address.
template<int PITCH>
__device__ __forceinline__ void radon_body(
    const float* __restrict__ img0, const float* __restrict__ img1,
    float* __restrict__ tA, float* __restrict__ tB, float2* __restrict__ red,
    float* __restrict__ out, float s, float c, int a, int w0, int A, int N)
{
    int lane = threadIdx.x & 63;
    int wv   = threadIdx.x >> 6;

    // ix(w,h) = c*u + s*t + 255.5, iy = -s*u + c*t + 255.5; u,t = coord-255.5
    float u   = (float)(w0 + lane) - 255.5f;
    float uc  = (float)w0 + (31.5f - 255.5f);
    float ex  = (fabsf(c) + s) * 31.5f;          // half-extent (square strip)
    float ixc = fmaf(c, uc, fmaf(s, (31.5f - 255.5f), 255.5f));
    float iyc = fmaf(-s, uc, fmaf(c, (31.5f - 255.5f), 255.5f));

    float acc0 = 0.0f, acc1 = 0.0f;
    for (int st = 0; st < NSTRIP; ++st) {
        int xmin = (int)floorf(ixc - ex) - 1;
        int ymin = (int)floorf(iyc - ex) - 1;
        int nxn  = min((int)floorf(ixc + ex) - xmin + 3, PITCH);  // 66..95
        int nyn  = min((int)floorf(iyc + ex) - ymin + 3, ROWS);

        if (st > 0) __syncthreads();             // prev strip's reads done

        bool border = (xmin < 0) | (ymin < 0) | (xmin + nxn > IMG) | (ymin + nyn > IMG);
        if (!border) {
            // interior: pure DMA; shared addressing, two images
            for (int yy = wv; yy < nyn; yy += HC) {
                size_t rowoff = (size_t)(ymin + yy) * IMG + xmin;
                const float* __restrict__ src0 = img0 + rowoff;
                const float* __restrict__ src1 = img1 + rowoff;
                float* dA = tA + __mul24(yy, PITCH);
                float* dB = tB + __mul24(yy, PITCH);
                gload_lds4(src0 + lane, dA);                     // nxn >= 66
                gload_lds4(src1 + lane, dB);
                if (64 + lane < nxn) {
                    gload_lds4(src0 + 64 + lane, dA + 64);
                    gload_lds4(src1 + 64 + lane, dB + 64);
                }
            }
        } else {
            // border: zero + DMA by the SAME wave (lgkmcnt orders within wave)
            int gx0 = max(xmin, 0), gx1 = min(xmin + nxn, IMG);
            int lx0 = gx0 - xmin, lxn = gx1 - gx0;
            for (int yy = wv; yy < nyn; yy += HC) {
                float* dA = tA + __mul24(yy, PITCH);
                float* dB = tB + __mul24(yy, PITCH);
                for (int xx = lane; xx < nxn; xx += 64) { dA[xx] = 0.0f; dB[xx] = 0.0f; }
            }
            asm volatile("s_waitcnt lgkmcnt(0)" ::: "memory");   // zeros landed
            if (lxn > 0) {
                for (int yy = wv; yy < nyn; yy += HC) {
                    int gy = ymin + yy;
                    if ((unsigned)gy < (unsigned)IMG) {
                        const float* __restrict__ src0 = img0 + (size_t)gy * IMG + gx0;
                        const float* __restrict__ src1 = img1 + (size_t)gy * IMG + gx0;
                        float* dA = tA + __mul24(yy, PITCH) + lx0;
                        float* dB = tB + __mul24(yy, PITCH) + lx0;
                        for (int k = 0; k < lxn; k += 64)
                            if (k + lane < lxn) {
                                gload_lds4(src0 + k + lane, dA + k);
                                gload_lds4(src1 + k + lane, dB + k);
                            }
                    }
                }
            }
        }
        __syncthreads();                         // DMA drained (vmcnt0 + barrier)

        // 8 samples along h; coords/weights/addresses shared across images
        float tb = (float)(st * HT + wv * HPER) - 255.5f;
        float fx = fmaf(s, tb, fmaf(c,  u, 255.5f - (float)xmin));
        float fy = fmaf(c, tb, fmaf(-s, u, 255.5f - (float)ymin));
        #pragma unroll
        for (int b = 0; b < HPER / 2; ++b) {
            float fx0 = fx,      fy0 = fy;
            float fx1 = fx + s,  fy1 = fy + c;
            fx = fx1 + s;  fy = fy1 + c;
            lerp_pair<PITCH>(tA, tB, fx0, fy0, acc0, acc1);
            lerp_pair<PITCH>(tA, tB, fx1, fy1, acc0, acc1);
        }

        ixc += s * (float)HT;                    // strip center advances along t
        iyc += c * (float)HT;
    }

    // reduce 8 wave-partials per w for both images; direct stores (no atomics)
    red[threadIdx.x] = make_float2(acc0, acc1);
    __syncthreads();
    if (threadIdx.x < WT) {
        float r0 = 0.0f, r1 = 0.0f;
        #pragma unroll
        for (int k = 0; k < HC; ++k) {
            float2 v = red[k * WT + threadIdx.x];
            r0 += v.x; r1 += v.y;
        }
        size_t w = (size_t)(w0 + threadIdx.x);
        out[w * A + a] = r0;                               // n = 0
        if (N > 1) out[((size_t)IMG + w) * A + a] = r1;    // n = 1
    }
}

__global__ __launch_bounds__(NT, 4) void radon_lds(
    const float* __restrict__ x, const float* __restrict__ theta,
    float* __restrict__ out, int N, int A)
{
    __shared__ float  tileA[BUF_FLOATS];   // statically distinct buffers:
    __shared__ float  tileB[BUF_FLOATS];   // runtime-selected LDS ptrs -> FLAT (r10)
    __shared__ float2 red[NT];
    int a  = blockIdx.z;
    int w0 = blockIdx.x * WT;

    float rad = theta[a] * 0.017453292519943295f;
    float s, c;
    __sincosf(rad, &s, &c);            // theta in [0,179] deg -> s >= 0

    const float* __restrict__ img0 = x;
    const float* __restrict__ img1 = (N > 1) ? (x + (size_t)IMG * IMG) : x;

    if (c * s >= 0.0f)
        radon_body<PITCH_A>(img0, img1, tileA, tileB, red, out, s, c, a, w0, A, N);
    else
        radon_body<PITCH_B>(img0, img1, tileA, tileB, red, out, s, c, a, w0, A, N);
}

extern "C" void kernel_launch(void* const* d_in, const int* in_sizes, int n_in,
                              void* d_out, int out_size, void* d_ws, size_t ws_size,
                              hipStream_t stream) {
    const float* x     = (const float*)d_in[0];
    const float* theta = (const float*)d_in[1];
    float* out = (float*)d_out;

    int A = in_sizes[1];                   // 180
    int N = in_sizes[0] / (IMG * IMG);     // 2

    dim3 grid(IMG / WT, 1, A);             // 8 x 1 x 180 = 1440 WGs (both images per WG)
    radon_lds<<<grid, NT, 0, stream>>>(x, theta, out, N, A);
}

// Round 15
// 101.199 us; speedup vs baseline: 4.5011x; 1.1157x over previous
//
#include <hip/hip_runtime.h>

#define IMG    512
#define WT     64          // w-tile (lanes)
#define HT     64          // h per strip
#define NSTRIP (IMG / HT)  // 8 strips -> one WG integrates the FULL line
#define NT     1024        // 16 waves -> 2 WG/CU = 32 waves/CU despite 74.6 KB LDS
#define HC     16          // h-chunks per strip (one per wave)
#define HPER   (HT / HC)   // 4 samples per thread per strip
#define ROWS   96          // staged rows (worst-case strip span ~95)
#define PITCH_A 95         // c*s >= 0  (95 % 32 == 31: bank ~ jx - jy, lane-step |c|+s)
#define PITCH_B 97         // c*s <  0  (97 % 32 ==  1: bank ~ jx + jy, lane-step |c|+s)
#define BUF_FLOATS (ROWS * PITCH_B + 8)   // 9320 floats = 37.3 KB per image tile

// Direct global->LDS DMA: wave-uniform LDS base, HW adds lane*4.
__device__ __forceinline__ void gload_lds4(const float* g, float* l) {
    __builtin_amdgcn_global_load_lds((const __attribute__((address_space(1))) void*)g,
                                     (__attribute__((address_space(3))) void*)l, 4, 0, 0);
}

// single-instruction fractional part
__device__ __forceinline__ float vfract(float x) {
    float r;
    asm("v_fract_f32 %0, %1" : "=v"(r) : "v"(x));
    return r;
}

// Bilinear taps for BOTH images at one sample point: address/weights computed
// once, tap reads + lerp duplicated.
template<int PITCH>
__device__ __forceinline__ void lerp_pair(const float* __restrict__ tA,
                                          const float* __restrict__ tB,
                                          float fx, float fy,
                                          float& a0, float& a1) {
    int jx = (int)fx;                  // fx,fy >= 1: trunc == floor
    int jy = (int)fy;
    int off = __mul24(jy, PITCH) + jx;
    const float* __restrict__ pA = tA + off;
    const float* __restrict__ pB = tB + off;
    float wx1 = vfract(fx);
    float wy1 = vfract(fy);
    float A00 = pA[0], A01 = pA[1];            // ds_read2 (0,1)
    float A10 = pA[PITCH], A11 = pA[PITCH+1];  // ds_read2 (P,P+1)
    float B00 = pB[0], B01 = pB[1];
    float B10 = pB[PITCH], B11 = pB[PITCH+1];
    float lA0 = fmaf(wx1, A01 - A00, A00);
    float lA1 = fmaf(wx1, A11 - A10, A10);
    float lB0 = fmaf(wx1, B01 - B00, B00);
    float lB1 = fmaf(wx1, B11 - B10, B10);
    a0 += fmaf(wy1, lA1 - lA0, lA0);
    a1 += fmaf(wy1, lB1 - lB0, lB0);
}

// One WG: full line integral for (w-tile, angle) for BOTH images.
template<int PITCH>
__device__ __forceinline__ void radon_body(
    const float* __restrict__ img0, const float* __restrict__ img1,
    float* __restrict__ tA, float* __restrict__ tB,
    float* __restrict__ out, float s, float c, int a, int w0, int A, int N)
{
    int lane = threadIdx.x & 63;
    int wv   = threadIdx.x >> 6;     // 16 waves

    // ix(w,h) = c*u + s*t + 255.5, iy = -s*u + c*t + 255.5; u,t = coord-255.5
    float u   = (float)(w0 + lane) - 255.5f;
    float uc  = (float)w0 + (31.5f - 255.5f);
    float ex  = (fabsf(c) + s) * 31.5f;          // half-extent (square strip)
    float ixc = fmaf(c, uc, fmaf(s, (31.5f - 255.5f), 255.5f));
    float iyc = fmaf(-s, uc, fmaf(c, (31.5f - 255.5f), 255.5f));

    float acc0 = 0.0f, acc1 = 0.0f;
    for (int st = 0; st < NSTRIP; ++st) {
        int xmin = (int)floorf(ixc - ex) - 1;
        int ymin = (int)floorf(iyc - ex) - 1;
        int nxn  = min((int)floorf(ixc + ex) - xmin + 3, PITCH);  // 66..95
        int nyn  = min((int)floorf(iyc + ex) - ymin + 3, ROWS);

        if (st > 0) __syncthreads();             // prev strip's reads done

        bool border = (xmin < 0) | (ymin < 0) | (xmin + nxn > IMG) | (ymin + nyn > IMG);
        if (!border) {
            // interior: pure DMA; shared addressing, two images
            for (int yy = wv; yy < nyn; yy += HC) {
                size_t rowoff = (size_t)(ymin + yy) * IMG + xmin;
                const float* __restrict__ src0 = img0 + rowoff;
                const float* __restrict__ src1 = img1 + rowoff;
                float* dA = tA + __mul24(yy, PITCH);
                float* dB = tB + __mul24(yy, PITCH);
                gload_lds4(src0 + lane, dA);                     // nxn >= 66
                gload_lds4(src1 + lane, dB);
                if (64 + lane < nxn) {
                    gload_lds4(src0 + 64 + lane, dA + 64);
                    gload_lds4(src1 + 64 + lane, dB + 64);
                }
            }
        } else {
            // border: zero + DMA by the SAME wave (lgkmcnt orders within wave)
            int gx0 = max(xmin, 0), gx1 = min(xmin + nxn, IMG);
            int lx0 = gx0 - xmin, lxn = gx1 - gx0;
            for (int yy = wv; yy < nyn; yy += HC) {
                float* dA = tA + __mul24(yy, PITCH);
                float* dB = tB + __mul24(yy, PITCH);
                for (int xx = lane; xx < nxn; xx += 64) { dA[xx] = 0.0f; dB[xx] = 0.0f; }
            }
            asm volatile("s_waitcnt lgkmcnt(0)" ::: "memory");   // zeros landed
            if (lxn > 0) {
                for (int yy = wv; yy < nyn; yy += HC) {
                    int gy = ymin + yy;
                    if ((unsigned)gy < (unsigned)IMG) {
                        const float* __restrict__ src0 = img0 + (size_t)gy * IMG + gx0;
                        const float* __restrict__ src1 = img1 + (size_t)gy * IMG + gx0;
                        float* dA = tA + __mul24(yy, PITCH) + lx0;
                        float* dB = tB + __mul24(yy, PITCH) + lx0;
                        for (int k = 0; k < lxn; k += 64)
                            if (k + lane < lxn) {
                                gload_lds4(src0 + k + lane, dA + k);
                                gload_lds4(src1 + k + lane, dB + k);
                            }
                    }
                }
            }
        }
        __syncthreads();                         // DMA drained (vmcnt0 + barrier)

        // 4 samples along h; coords/weights/addresses shared across images
        float tb = (float)(st * HT + wv * HPER) - 255.5f;
        float fx = fmaf(s, tb, fmaf(c,  u, 255.5f - (float)xmin));
        float fy = fmaf(c, tb, fmaf(-s, u, 255.5f - (float)ymin));
        #pragma unroll
        for (int b = 0; b < HPER / 2; ++b) {
            float fx0 = fx,      fy0 = fy;
            float fx1 = fx + s,  fy1 = fy + c;
            fx = fx1 + s;  fy = fy1 + c;
            lerp_pair<PITCH>(tA, tB, fx0, fy0, acc0, acc1);
            lerp_pair<PITCH>(tA, tB, fx1, fy1, acc0, acc1);
        }

        ixc += s * (float)HT;                    // strip center advances along t
        iyc += c * (float)HT;
    }

    // reduce 16 wave-partials per w. tile reads are done (barrier), so reuse
    // tileA's storage for the reduction scratch (same static LDS object).
    __syncthreads();
    float2* red = (float2*)tA;
    red[threadIdx.x] = make_float2(acc0, acc1);
    __syncthreads();
    if (threadIdx.x < WT) {
        float r0 = 0.0f, r1 = 0.0f;
        #pragma unroll
        for (int k = 0; k < HC; ++k) {
            float2 v = red[k * WT + threadIdx.x];
            r0 += v.x; r1 += v.y;
        }
        size_t w = (size_t)(w0 + threadIdx.x);
        out[w * A + a] = r0;                               // n = 0
        if (N > 1) out[((size_t)IMG + w) * A + a] = r1;    // n = 1
    }
}

__global__ __launch_bounds__(NT, 8) void radon_lds(
    const float* __restrict__ x, const float* __restrict__ theta,
    float* __restrict__ out, int N, int A)
{
    __shared__ __align__(16) float tileA[BUF_FLOATS];  // statically distinct buffers:
    __shared__ __align__(16) float tileB[BUF_FLOATS];  // runtime LDS ptr select -> FLAT (r10)
    int a  = blockIdx.z;
    int w0 = blockIdx.x * WT;

    float rad = theta[a] * 0.017453292519943295f;
    float s, c;
    __sincosf(rad, &s, &c);            // theta in [0,179] deg -> s >= 0

    const float* __restrict__ img0 = x;
    const float* __restrict__ img1 = (N > 1) ? (x + (size_t)IMG * IMG) : x;

    if (c * s >= 0.0f)
        radon_body<PITCH_A>(img0, img1, tileA, tileB, out, s, c, a, w0, A, N);
    else
        radon_body<PITCH_B>(img0, img1, tileA, tileB, out, s, c, a, w0, A, N);
}

extern "C" void kernel_launch(void* const* d_in, const int* in_sizes, int n_in,
                              void* d_out, int out_size, void* d_ws, size_t ws_size,
                              hipStream_t stream) {
    const float* x     = (const float*)d_in[0];
    const float* theta = (const float*)d_in[1];
    float* out = (float*)d_out;

    int A = in_sizes[1];                   // 180
    int N = in_sizes[0] / (IMG * IMG);     // 2

    dim3 grid(IMG / WT, 1, A);             // 8 x 1 x 180 = 1440 WGs (both images per WG)
    radon_lds<<<grid, NT, 0, stream>>>(x, theta, out, N, A);
}